// Round 8
// baseline (1627.044 us; speedup 1.0000x reference)
//
#include <hip/hip_runtime.h>
#include <hip/hip_bf16.h>

#define N_NODES    100000
#define N_EDGES    1600000
#define IN_CH      128
#define HID        64
#define N_LAYERS   4
#define OUT_CH     10
#define NUM_GRAPHS 128
#define BN_EPS     1e-5f
#define SCAN_NB    391            // ceil(100000/256)

typedef __hip_bfloat16 bf16;
typedef unsigned int uint32;

// unpack packed bf16x2 -> float2 (bf16 -> f32 is just <<16)
__device__ __forceinline__ float2 unpk(uint32 p) {
    float2 r;
    r.x = __uint_as_float(p << 16);
    r.y = __uint_as_float(p & 0xffff0000u);
    return r;
}

// ---------------- utility zeroing ----------------
__global__ void zero_i(int* __restrict__ p, int n) {
    int i = blockIdx.x * 256 + threadIdx.x;
    int st = gridDim.x * 256;
    for (; i < n; i += st) p[i] = 0;
}

// ---------------- CSR build: rows = dst, cols = src --------------------------
__global__ void hist(const int* __restrict__ dst, int* __restrict__ cnt) {
    int e = blockIdx.x * 256 + threadIdx.x;       // 6250 * 256 == 1.6M exact
    atomicAdd(&cnt[dst[e]], 1);
}

__global__ void scan_local(const int* __restrict__ cnt, int* __restrict__ row_start,
                           int* __restrict__ bsum) {
    __shared__ int sh[256];
    int t = threadIdx.x, i = blockIdx.x * 256 + t;
    int v = (i < N_NODES) ? cnt[i] : 0;
    sh[t] = v;
    __syncthreads();
    for (int off = 1; off < 256; off <<= 1) {
        int add = (t >= off) ? sh[t - off] : 0;
        __syncthreads();
        sh[t] += add;
        __syncthreads();
    }
    if (i < N_NODES) row_start[i] = sh[t] - v;    // exclusive
    if (t == 255) bsum[blockIdx.x] = sh[255];
}

// parallel exclusive scan of chunk totals + zero `pooled` (merged)
__global__ void scan_bsum(int* __restrict__ bsum, float* __restrict__ pooled) {
    __shared__ int sh[512];
    int t = threadIdx.x;
    int v = (t < SCAN_NB) ? bsum[t] : 0;
    sh[t] = v;
    __syncthreads();
    for (int off = 1; off < 512; off <<= 1) {
        int add = (t >= off) ? sh[t - off] : 0;
        __syncthreads();
        sh[t] += add;
        __syncthreads();
    }
    if (t < SCAN_NB) bsum[t] = sh[t] - v;         // exclusive
    for (int i = t; i < NUM_GRAPHS * HID; i += 512) pooled[i] = 0.f;
}

__global__ void add_off(int* __restrict__ row_start, const int* __restrict__ bsum) {
    int i = blockIdx.x * 256 + threadIdx.x;
    if (i < N_NODES) row_start[i] += bsum[blockIdx.x];
    if (i == 0) row_start[N_NODES] = N_EDGES;
}

__global__ void fill_csr(const int* __restrict__ src, const int* __restrict__ dst,
                         const int* __restrict__ row_start, int* __restrict__ cur,
                         int* __restrict__ col) {
    int e = blockIdx.x * 256 + threadIdx.x;       // 6250 * 256
    int d = dst[e];
    int slot = row_start[d] + atomicAdd(&cur[d], 1);
    col[slot] = src[e];
}

// ---------------- layer-0 pre-projection: ybf = bf16(x @ W1f), packed --------
// 2 nodes per wave; lane = (half, l): computes channels 2l,2l+1 of its node.
__global__ void proj0(const float* __restrict__ x, const float* __restrict__ W1,
                      uint32* __restrict__ ybf) {
    __shared__ float xsh[4][2 * IN_CH];           // 2 nodes x 128 per wave
    const int wave = threadIdx.x >> 6, lane = threadIdx.x & 63;
    const int half = lane >> 5, l = lane & 31;
    const int nA = blockIdx.x * 8 + wave * 2;     // 12500 blocks * 8 == 100000
    const int n_h = nA + half;

    // stage both rows: 256 floats, 4 per lane, fully coalesced
    float4 xv = ((const float4*)(x + (long)nA * IN_CH))[lane];
    *(float4*)&xsh[wave][lane * 4] = xv;
    // per-wave LDS slice: wave-lockstep + compiler lgkmcnt; no barrier

    const float* xb = &xsh[wave][half * IN_CH];
    float2 a0 = {0.f, 0.f}, a1 = {0.f, 0.f}, a2 = {0.f, 0.f}, a3 = {0.f, 0.f};
    for (int k = 0; k < IN_CH; k += 4) {
        float4 q = *(const float4*)&xb[k];
        float2 w0 = ((const float2*)(W1 + (k + 0) * 64))[l];
        float2 w1 = ((const float2*)(W1 + (k + 1) * 64))[l];
        float2 w2 = ((const float2*)(W1 + (k + 2) * 64))[l];
        float2 w3 = ((const float2*)(W1 + (k + 3) * 64))[l];
        a0.x += q.x * w0.x; a0.y += q.x * w0.y;
        a1.x += q.y * w1.x; a1.y += q.y * w1.y;
        a2.x += q.z * w2.x; a2.y += q.z * w2.y;
        a3.x += q.w * w3.x; a3.y += q.w * w3.y;
    }
    float vx = (a0.x + a1.x) + (a2.x + a3.x);
    float vy = (a0.y + a1.y) + (a2.y + a3.y);
    __hip_bfloat162 pb;
    pb.x = __float2bfloat16(vx);
    pb.y = __float2bfloat16(vy);
    ybf[(long)n_h * 32 + l] = *(uint32*)&pb;
}

// ---------------- fused layer: gather -> relu -> W2 -> JK (+ next W1) --------
// 2 nodes per wave; payloads are packed bf16x2 dwords.
template <bool FIRST, bool HAS_NEXT>
__global__ void layer_fused(const uint32* __restrict__ ybf,
                            const int* __restrict__ row_start, const int* __restrict__ col,
                            const float* __restrict__ b1, const float* __restrict__ W2,
                            const float* __restrict__ b2, const float* __restrict__ Wjk_blk,
                            const float* __restrict__ W1n,
                            uint32* __restrict__ ynext_bf, float2* __restrict__ jk2) {
    __shared__ float tsh[4][2 * HID];
    __shared__ float hsh[4][2 * HID];
    const int wave = threadIdx.x >> 6, lane = threadIdx.x & 63;
    const int half = lane >> 5, l = lane & 31;
    const int nA = blockIdx.x * 8 + wave * 2;     // 12500 blocks
    const int n_h = nA + half;

    // uniform row bounds (s_loads)
    const int rsA = row_start[nA];
    const int rsB = row_start[nA + 1];
    const int rsE = row_start[nA + 2];
    const int degA = rsB - rsA, degB = rsE - rsB;
    const int s_h  = half ? rsB : rsA;
    const int deg_h = half ? degB : degA;
    const int kmax = max(degA, degB);
    const int safe = (deg_h > 0) ? s_h : 0;       // valid col slot for padding

    // self + bias
    float2 bb = ((const float2*)b1)[l];
    float2 a0 = unpk(ybf[(long)n_h * 32 + l]);
    a0.x += bb.x; a0.y += bb.y;
    float2 a1 = {0.f, 0.f}, a2 = {0.f, 0.f}, a3 = {0.f, 0.f};

    for (int k = 0; k < kmax; k += 8) {
        uint32 p[8];
        bool v[8];
        #pragma unroll
        for (int u = 0; u < 8; u++) {
            int i = k + u;
            v[u] = i < deg_h;
            int ii = v[u] ? (s_h + i) : safe;
            int c = col[ii];
            p[u] = ybf[(long)c * 32 + l];
        }
        #pragma unroll
        for (int u = 0; u < 8; u++) {
            uint32 q = v[u] ? p[u] : 0u;          // unpk(0) == {0,0}
            float2 f = unpk(q);
            if ((u & 3) == 0) { a0.x += f.x; a0.y += f.y; }
            else if ((u & 3) == 1) { a1.x += f.x; a1.y += f.y; }
            else if ((u & 3) == 2) { a2.x += f.x; a2.y += f.y; }
            else { a3.x += f.x; a3.y += f.y; }
        }
    }
    float2 t;
    t.x = fmaxf((a0.x + a1.x) + (a2.x + a3.x), 0.f);
    t.y = fmaxf((a0.y + a1.y) + (a2.y + a3.y), 0.f);
    ((float2*)&tsh[wave][half * HID])[l] = t;     // 2-way bank alias: free

    // h = relu(t @ W2 + b2) — 4x float2 accumulators, W2 rows shared by halves
    const float* tb = &tsh[wave][half * HID];
    float2 h0 = ((const float2*)b2)[l];
    float2 h1 = {0.f, 0.f}, h2 = {0.f, 0.f}, h3 = {0.f, 0.f};
    for (int k = 0; k < 64; k += 4) {
        float4 tv = *(const float4*)&tb[k];
        float2 w0 = ((const float2*)(W2 + (k + 0) * 64))[l];
        float2 w1 = ((const float2*)(W2 + (k + 1) * 64))[l];
        float2 w2 = ((const float2*)(W2 + (k + 2) * 64))[l];
        float2 w3 = ((const float2*)(W2 + (k + 3) * 64))[l];
        h0.x += tv.x * w0.x; h0.y += tv.x * w0.y;
        h1.x += tv.y * w1.x; h1.y += tv.y * w1.y;
        h2.x += tv.z * w2.x; h2.y += tv.z * w2.y;
        h3.x += tv.w * w3.x; h3.y += tv.w * w3.y;
    }
    float2 h;
    h.x = fmaxf((h0.x + h1.x) + (h2.x + h3.x), 0.f);
    h.y = fmaxf((h0.y + h1.y) + (h2.y + h3.y), 0.f);
    ((float2*)&hsh[wave][half * HID])[l] = h;

    // j = h @ Wjk_blk ; yn = h @ W1n (interleaved chains)
    const float* hb = &hsh[wave][half * HID];
    float2 j0 = {0.f, 0.f}, j1 = {0.f, 0.f};
    float2 y0 = {0.f, 0.f}, y1 = {0.f, 0.f};
    for (int k = 0; k < 64; k += 4) {
        float4 hv = *(const float4*)&hb[k];
        float2 wj0 = ((const float2*)(Wjk_blk + (k + 0) * 64))[l];
        float2 wj1 = ((const float2*)(Wjk_blk + (k + 1) * 64))[l];
        float2 wj2 = ((const float2*)(Wjk_blk + (k + 2) * 64))[l];
        float2 wj3 = ((const float2*)(Wjk_blk + (k + 3) * 64))[l];
        j0.x += hv.x * wj0.x; j0.y += hv.x * wj0.y;
        j1.x += hv.y * wj1.x; j1.y += hv.y * wj1.y;
        j0.x += hv.z * wj2.x; j0.y += hv.z * wj2.y;
        j1.x += hv.w * wj3.x; j1.y += hv.w * wj3.y;
        if (HAS_NEXT) {
            float2 wn0 = ((const float2*)(W1n + (k + 0) * 64))[l];
            float2 wn1 = ((const float2*)(W1n + (k + 1) * 64))[l];
            float2 wn2 = ((const float2*)(W1n + (k + 2) * 64))[l];
            float2 wn3 = ((const float2*)(W1n + (k + 3) * 64))[l];
            y0.x += hv.x * wn0.x; y0.y += hv.x * wn0.y;
            y1.x += hv.y * wn1.x; y1.y += hv.y * wn1.y;
            y0.x += hv.z * wn2.x; y0.y += hv.z * wn2.y;
            y1.x += hv.w * wn3.x; y1.y += hv.w * wn3.y;
        }
    }
    const long idx2 = (long)n_h * 32 + l;
    float2 jv; jv.x = j0.x + j1.x; jv.y = j0.y + j1.y;
    if (FIRST) {
        jk2[idx2] = jv;
    } else {
        float2 old = jk2[idx2];
        old.x += jv.x; old.y += jv.y;
        jk2[idx2] = old;
    }
    if (HAS_NEXT) {
        __hip_bfloat162 pb;
        pb.x = __float2bfloat16(y0.x + y1.x);
        pb.y = __float2bfloat16(y0.y + y1.y);
        ynext_bf[idx2] = *(uint32*)&pb;
    }
}

// ---------------- global add pool (batch is sorted) --------------------------
__global__ void pool_kernel(const float* __restrict__ jk, const int* __restrict__ batch,
                            const float* __restrict__ bjk, float* __restrict__ pooled) {
    const int NPB = 125;                          // 800 * 125 == 100000
    int s = blockIdx.x * NPB, e = s + NPB;
    int lane = threadIdx.x;                       // 64 threads
    float bj = bjk[lane];
    float acc = 0.f;
    int gcur = batch[s];
    for (int n = s; n < e; n++) {
        int g = batch[n];
        if (g != gcur) {
            atomicAdd(pooled + gcur * 64 + lane, acc);
            acc = 0.f; gcur = g;
        }
        acc += jk[(long)n * 64 + lane] + bj;
    }
    atomicAdd(pooled + gcur * 64 + lane, acc);
}

// ---------------- classifier: one kernel (Linear -> BN -> ReLU -> Linear) ----
__global__ void cls_all(const float* __restrict__ pooled,
                        const float* __restrict__ Wc1, const float* __restrict__ bc1,
                        const float* __restrict__ gamma, const float* __restrict__ beta,
                        const float* __restrict__ Wc2, const float* __restrict__ bc2,
                        float* __restrict__ out) {
    __shared__ float Z[NUM_GRAPHS * HID];         // 32 KB
    __shared__ float mu[HID], rs[HID];
    int tid = threadIdx.x;                        // 256

    for (int i = tid; i < NUM_GRAPHS * HID; i += 256) {
        int g = i >> 6, j = i & 63;
        float acc = bc1[j];
        for (int k = 0; k < 64; k++) acc += pooled[g * 64 + k] * Wc1[k * 64 + j];
        Z[i] = acc;
    }
    __syncthreads();
    if (tid < HID) {
        float s = 0.f, sq = 0.f;
        for (int g = 0; g < NUM_GRAPHS; g++) {
            float v = Z[g * 64 + tid];
            s += v; sq += v * v;
        }
        float m = s / NUM_GRAPHS;
        mu[tid] = m;
        rs[tid] = rsqrtf(sq / NUM_GRAPHS - m * m + BN_EPS);
    }
    __syncthreads();
    for (int i = tid; i < NUM_GRAPHS * OUT_CH; i += 256) {
        int g = i / OUT_CH, o = i % OUT_CH;
        float acc = bc2[o];
        for (int j = 0; j < 64; j++) {
            float v = (Z[g * 64 + j] - mu[j]) * rs[j] * gamma[j] + beta[j];
            acc += fmaxf(v, 0.f) * Wc2[j * OUT_CH + o];
        }
        out[i] = acc;
    }
}

// -----------------------------------------------------------------------------
extern "C" void kernel_launch(void* const* d_in, const int* in_sizes, int n_in,
                              void* d_out, int out_size, void* d_ws, size_t ws_size,
                              hipStream_t stream) {
    const float* x     = (const float*)d_in[0];
    const int*   ei    = (const int*)d_in[1];
    const int*   batch = (const int*)d_in[2];
    const float* W1f   = (const float*)d_in[3];
    const float* b1f   = (const float*)d_in[4];
    const float* W2f   = (const float*)d_in[5];
    const float* b2f   = (const float*)d_in[6];
    const float* W1r   = (const float*)d_in[7];
    const float* b1r   = (const float*)d_in[8];
    const float* W2r   = (const float*)d_in[9];
    const float* b2r   = (const float*)d_in[10];
    const float* Wjk   = (const float*)d_in[11];
    const float* bjk   = (const float*)d_in[12];
    const float* Wc1   = (const float*)d_in[13];
    const float* bc1   = (const float*)d_in[14];
    const float* gamma = (const float*)d_in[15];
    const float* beta  = (const float*)d_in[16];
    const float* Wc2   = (const float*)d_in[17];
    const float* bc2   = (const float*)d_in[18];

    const int* src = ei;
    const int* dst = ei + N_EDGES;

    // workspace layout
    float*  ws     = (float*)d_ws;
    float*  jk     = ws;                                   // 6.4M floats
    float*  zpad   = jk + (long)N_NODES * HID;
    float*  pooled = zpad;                                 // 8192
    uint32* ybfA   = (uint32*)(pooled + NUM_GRAPHS * HID); // 3.2M uints
    uint32* ybfB   = ybfA + (long)N_NODES * 32;            // 3.2M uints
    int*    row_start = (int*)(ybfB + (long)N_NODES * 32); // 100001
    int*    cnt    = row_start + N_NODES + 8;              // 100000
    int*    cur    = cnt + N_NODES;                        // 100000
    int*    bsum   = cur + N_NODES;                        // 391(+pad)
    int*    col    = bsum + 512;                           // 1.6M

    // ---- CSR build (rows = dst, cols = src) ----
    zero_i<<<256, 256, 0, stream>>>(cnt, 2 * N_NODES);     // cnt + cur in one pass
    hist<<<N_EDGES / 256, 256, 0, stream>>>(dst, cnt);
    scan_local<<<SCAN_NB, 256, 0, stream>>>(cnt, row_start, bsum);
    scan_bsum<<<1, 512, 0, stream>>>(bsum, pooled);        // + pooled zeroing
    add_off<<<SCAN_NB, 256, 0, stream>>>(row_start, bsum);
    fill_csr<<<N_EDGES / 256, 256, 0, stream>>>(src, dst, row_start, cur, col);

    // ---- layer-0 pre-projection (dense, streaming) ----
    const int NB = N_NODES / 8;                            // 12500
    proj0<<<NB, 256, 0, stream>>>(x, W1f, ybfA);

    // ---- 4 fused layers ----
    layer_fused<true, true><<<NB, 256, 0, stream>>>(
        ybfA, row_start, col, b1f, W2f, b2f, Wjk,
        W1r, ybfB, (float2*)jk);
    layer_fused<false, true><<<NB, 256, 0, stream>>>(
        ybfB, row_start, col, b1r, W2r, b2r, Wjk + (long)1 * HID * HID,
        W1r + (long)1 * HID * HID, ybfA, (float2*)jk);
    layer_fused<false, true><<<NB, 256, 0, stream>>>(
        ybfA, row_start, col, b1r + HID, W2r + (long)1 * HID * HID, b2r + HID,
        Wjk + (long)2 * HID * HID, W1r + (long)2 * HID * HID, ybfB, (float2*)jk);
    layer_fused<false, false><<<NB, 256, 0, stream>>>(
        ybfB, row_start, col, b1r + 2 * HID, W2r + (long)2 * HID * HID,
        b2r + 2 * HID, Wjk + (long)3 * HID * HID, nullptr, nullptr, (float2*)jk);

    // ---- JK bias + global add pool ----
    pool_kernel<<<N_NODES / 125, 64, 0, stream>>>(jk, batch, bjk, pooled);

    // ---- classifier (single kernel) ----
    cls_all<<<1, 256, 0, stream>>>(pooled, Wc1, bc1, gamma, beta, Wc2, bc2,
                                   (float*)d_out);
}

// Round 9
// 1261.265 us; speedup vs baseline: 1.2900x; 1.2900x over previous
//
#include <hip/hip_runtime.h>
#include <hip/hip_bf16.h>

#define N_NODES    100000
#define N_EDGES    1600000
#define IN_CH      128
#define HID        64
#define N_LAYERS   4
#define OUT_CH     10
#define NUM_GRAPHS 128
#define BN_EPS     1e-5f
#define CAP        64             // padded CSR row capacity; P(deg>64) ~ 1e-19 at Poisson(16)

typedef __hip_bfloat16 bf16;
__device__ __forceinline__ float bf2f(bf16 v) { return __bfloat162float(v); }

// ---------------- zero the counter/accumulator region ------------------------
__global__ void zero_i(int* __restrict__ p, int n) {
    int i = blockIdx.x * 256 + threadIdx.x;
    int st = gridDim.x * 256;
    for (; i < n; i += st) p[i] = 0;
}

// ---------------- padded CSR fill: col[d*CAP + slot] = src --------------------
__global__ void fill_padded(const int* __restrict__ src, const int* __restrict__ dst,
                            int* __restrict__ cnt, int* __restrict__ col) {
    int e = blockIdx.x * 256 + threadIdx.x;       // 6250 * 256 == 1.6M exact
    int d = dst[e];
    int slot = atomicAdd(&cnt[d], 1);             // slot < CAP (see header note)
    col[d * CAP + slot] = src[e];
}

// ---------------- per-graph node counts (batch histogram) --------------------
__global__ void cntg_hist(const int* __restrict__ batch, int* __restrict__ cntg) {
    int i = blockIdx.x * 256 + threadIdx.x;       // 391 blocks
    if (i < N_NODES) atomicAdd(&cntg[batch[i]], 1);
}

// ---------------- layer-0 pre-projection: ybf = bf16(x @ W1f) (no bias) ------
__global__ void proj0(const float* __restrict__ x, const float* __restrict__ W1,
                      bf16* __restrict__ ybf) {
    __shared__ float xsh[4][IN_CH];
    const int wave = threadIdx.x >> 6, lane = threadIdx.x & 63;
    const int n = blockIdx.x * 4 + wave;          // 25000 * 4 == 100000
    float2 xv2 = ((const float2*)(x + (long)n * IN_CH))[lane];
    xsh[wave][2 * lane]     = xv2.x;              // 2-way bank alias: free
    xsh[wave][2 * lane + 1] = xv2.y;
    // per-wave LDS slice: wave-lockstep + compiler lgkmcnt; no barrier
    float acc = 0.f;
    for (int k = 0; k < IN_CH; k += 4) {
        float4 xv = *(const float4*)&xsh[wave][k];
        acc += xv.x * W1[(k + 0) * 64 + lane];
        acc += xv.y * W1[(k + 1) * 64 + lane];
        acc += xv.z * W1[(k + 2) * 64 + lane];
        acc += xv.w * W1[(k + 3) * 64 + lane];
    }
    ybf[(long)n * 64 + lane] = __float2bfloat16(acc);
}

// ---------------- fused layer: gather -> relu -> W2 -> pool (+ next W1) ------
// t = relu( ybf[n] + sum_nb ybf[nb] + b1 );  h = relu(t@W2 + b2)
// pooled_l[batch[n]] += h (atomic, exact-linearity JK-after-pool trick)
// if HAS_NEXT: ynext = bf16(h @ W1n)
template <bool HAS_NEXT>
__global__ void layer_fused(const bf16* __restrict__ ybf, const int* __restrict__ cnt,
                            const int* __restrict__ col, const int* __restrict__ batch,
                            const float* __restrict__ b1, const float* __restrict__ W2,
                            const float* __restrict__ b2, const float* __restrict__ W1n,
                            bf16* __restrict__ ynext, float* __restrict__ pooled_l) {
    __shared__ float tsh[4][64];
    __shared__ float hsh[4][64];
    const int wave = threadIdx.x >> 6, lane = threadIdx.x & 63;
    const int n = __builtin_amdgcn_readfirstlane(blockIdx.x * 4 + wave);
    const int deg = __builtin_amdgcn_readfirstlane(cnt[n]);
    const int g = __builtin_amdgcn_readfirstlane(batch[n]);
    const long s = (long)n * CAP;

    float t = bf2f(ybf[(long)n * 64 + lane]) + b1[lane];

    // 16-deep batches (R7-proven): 16 outstanding row-gathers per wave
    int i = 0;
    for (; i + 16 <= deg; i += 16) {
        float f[16];
        #pragma unroll
        for (int u = 0; u < 16; u++) {
            int c = __builtin_amdgcn_readfirstlane(col[s + i + u]);
            f[u] = bf2f(ybf[(long)c * 64 + lane]);
        }
        #pragma unroll
        for (int u = 0; u < 16; u++) t += f[u];
    }
    for (; i + 4 <= deg; i += 4) {
        float f[4];
        #pragma unroll
        for (int u = 0; u < 4; u++) {
            int c = __builtin_amdgcn_readfirstlane(col[s + i + u]);
            f[u] = bf2f(ybf[(long)c * 64 + lane]);
        }
        t += (f[0] + f[1]) + (f[2] + f[3]);
    }
    for (; i < deg; i++) {
        int c = __builtin_amdgcn_readfirstlane(col[s + i]);
        t += bf2f(ybf[(long)c * 64 + lane]);
    }
    t = fmaxf(t, 0.f);
    tsh[wave][lane] = t;          // per-wave slice: no __syncthreads anywhere

    float h = b2[lane];
    for (int k = 0; k < 64; k += 4) {
        float4 tv = *(const float4*)&tsh[wave][k];
        h += tv.x * W2[(k + 0) * 64 + lane];
        h += tv.y * W2[(k + 1) * 64 + lane];
        h += tv.z * W2[(k + 2) * 64 + lane];
        h += tv.w * W2[(k + 3) * 64 + lane];
    }
    h = fmaxf(h, 0.f);

    // global-add-pool contribution (32-KB L2-resident target)
    atomicAdd(&pooled_l[g * 64 + lane], h);

    if (HAS_NEXT) {
        hsh[wave][lane] = h;
        float yn = 0.f;
        for (int k = 0; k < 64; k += 4) {
            float4 hv = *(const float4*)&hsh[wave][k];
            yn += hv.x * W1n[(k + 0) * 64 + lane];
            yn += hv.y * W1n[(k + 1) * 64 + lane];
            yn += hv.z * W1n[(k + 2) * 64 + lane];
            yn += hv.w * W1n[(k + 3) * 64 + lane];
        }
        ynext[(long)n * 64 + lane] = __float2bfloat16(yn);
    }
}

// ---------------- JK projection on pooled sums (exact: pooling is linear) ----
// pooled_jk[g] = sum_l pooled_l[g] @ Wjk_l + cntg[g] * bjk
__global__ void jk_pool(const float* __restrict__ pooled, const int* __restrict__ cntg,
                        const float* __restrict__ Wjk, const float* __restrict__ bjk,
                        float* __restrict__ pooled_jk) {
    int g = blockIdx.x, j = threadIdx.x;          // 128 blocks x 64 threads
    float acc = (float)cntg[g] * bjk[j];
    for (int l = 0; l < N_LAYERS; l++) {
        const float* pg = pooled + (long)l * NUM_GRAPHS * HID + g * 64;
        const float* W  = Wjk + (long)l * HID * 64;
        for (int k = 0; k < 64; k++) acc += pg[k] * W[k * 64 + j];
    }
    pooled_jk[g * 64 + j] = acc;
}

// ---------------- classifier: Linear -> BN(batch stats) -> ReLU -> Linear ----
__global__ void cls_all(const float* __restrict__ pooled_jk,
                        const float* __restrict__ Wc1, const float* __restrict__ bc1,
                        const float* __restrict__ gamma, const float* __restrict__ beta,
                        const float* __restrict__ Wc2, const float* __restrict__ bc2,
                        float* __restrict__ out) {
    __shared__ float Z[NUM_GRAPHS * HID];         // 32 KB
    __shared__ float mu[HID], rs[HID];
    int tid = threadIdx.x;                        // 256

    for (int i = tid; i < NUM_GRAPHS * HID; i += 256) {
        int g = i >> 6, j = i & 63;
        float acc = bc1[j];
        for (int k = 0; k < 64; k++) acc += pooled_jk[g * 64 + k] * Wc1[k * 64 + j];
        Z[i] = acc;
    }
    __syncthreads();
    if (tid < HID) {
        float s = 0.f, sq = 0.f;
        for (int g = 0; g < NUM_GRAPHS; g++) {
            float v = Z[g * 64 + tid];
            s += v; sq += v * v;
        }
        float m = s / NUM_GRAPHS;
        mu[tid] = m;
        rs[tid] = rsqrtf(sq / NUM_GRAPHS - m * m + BN_EPS);
    }
    __syncthreads();
    for (int i = tid; i < NUM_GRAPHS * OUT_CH; i += 256) {
        int g = i / OUT_CH, o = i % OUT_CH;
        float acc = bc2[o];
        for (int j = 0; j < 64; j++) {
            float v = (Z[g * 64 + j] - mu[j]) * rs[j] * gamma[j] + beta[j];
            acc += fmaxf(v, 0.f) * Wc2[j * OUT_CH + o];
        }
        out[i] = acc;
    }
}

// -----------------------------------------------------------------------------
extern "C" void kernel_launch(void* const* d_in, const int* in_sizes, int n_in,
                              void* d_out, int out_size, void* d_ws, size_t ws_size,
                              hipStream_t stream) {
    const float* x     = (const float*)d_in[0];
    const int*   ei    = (const int*)d_in[1];
    const int*   batch = (const int*)d_in[2];
    const float* W1f   = (const float*)d_in[3];
    const float* b1f   = (const float*)d_in[4];
    const float* W2f   = (const float*)d_in[5];
    const float* b2f   = (const float*)d_in[6];
    const float* W1r   = (const float*)d_in[7];
    const float* b1r   = (const float*)d_in[8];
    const float* W2r   = (const float*)d_in[9];
    const float* b2r   = (const float*)d_in[10];
    const float* Wjk   = (const float*)d_in[11];
    const float* bjk   = (const float*)d_in[12];
    const float* Wc1   = (const float*)d_in[13];
    const float* bc1   = (const float*)d_in[14];
    const float* gamma = (const float*)d_in[15];
    const float* beta  = (const float*)d_in[16];
    const float* Wc2   = (const float*)d_in[17];
    const float* bc2   = (const float*)d_in[18];

    const int* src = ei;
    const int* dst = ei + N_EDGES;

    // workspace layout
    float* ws        = (float*)d_ws;
    float* pooled_jk = ws;                                  // 8192 floats
    bf16*  ybfA      = (bf16*)(pooled_jk + NUM_GRAPHS * HID);   // 6.4M bf16
    bf16*  ybfB      = ybfA + (long)N_NODES * HID;              // 6.4M bf16
    int*   cnt       = (int*)(ybfB + (long)N_NODES * HID);      // 100000
    int*   cntg      = cnt + N_NODES;                           // 128
    float* pooled    = (float*)(cntg + NUM_GRAPHS);             // 4*8192 floats
    int*   col       = (int*)(pooled + N_LAYERS * NUM_GRAPHS * HID); // 6.4M ints
    const int ZN = N_NODES + NUM_GRAPHS + N_LAYERS * NUM_GRAPHS * HID; // cnt..pooled

    // ---- build padded CSR + per-graph counts (zero cnt/cntg/pooled first) ----
    zero_i<<<130, 256, 0, stream>>>(cnt, ZN);
    fill_padded<<<N_EDGES / 256, 256, 0, stream>>>(src, dst, cnt, col);
    cntg_hist<<<(N_NODES + 255) / 256, 256, 0, stream>>>(batch, cntg);

    // ---- layer-0 pre-projection (dense, streaming) ----
    const int NB = N_NODES / 4;                             // 25000
    proj0<<<NB, 256, 0, stream>>>(x, W1f, ybfA);

    // ---- 4 fused layers ----
    layer_fused<true><<<NB, 256, 0, stream>>>(
        ybfA, cnt, col, batch, b1f, W2f, b2f,
        W1r, ybfB, pooled);
    layer_fused<true><<<NB, 256, 0, stream>>>(
        ybfB, cnt, col, batch, b1r, W2r, b2r,
        W1r + (long)1 * HID * HID, ybfA, pooled + 1 * NUM_GRAPHS * HID);
    layer_fused<true><<<NB, 256, 0, stream>>>(
        ybfA, cnt, col, batch, b1r + HID, W2r + (long)1 * HID * HID, b2r + HID,
        W1r + (long)2 * HID * HID, ybfB, pooled + 2 * NUM_GRAPHS * HID);
    layer_fused<false><<<NB, 256, 0, stream>>>(
        ybfB, cnt, col, batch, b1r + 2 * HID, W2r + (long)2 * HID * HID, b2r + 2 * HID,
        nullptr, nullptr, pooled + 3 * NUM_GRAPHS * HID);

    // ---- JK on pooled sums + classifier ----
    jk_pool<<<NUM_GRAPHS, 64, 0, stream>>>(pooled, cntg, Wjk, bjk, pooled_jk);
    cls_all<<<1, 256, 0, stream>>>(pooled_jk, Wc1, bc1, gamma, beta, Wc2, bc2,
                                   (float*)d_out);
}

// Round 10
// 858.249 us; speedup vs baseline: 1.8958x; 1.4696x over previous
//
#include <hip/hip_runtime.h>
#include <hip/hip_bf16.h>

#define N_NODES    100000
#define N_EDGES    1600000
#define IN_CH      128
#define HID        64
#define N_LAYERS   4
#define OUT_CH     10
#define NUM_GRAPHS 128
#define BN_EPS     1e-5f
#define CAP        64             // padded CSR row capacity; P(deg>64) ~ 1e-19 at Poisson(16)
#define NREP       8              // pooled replicas (cuts per-address atomic chains 8x)

typedef __hip_bfloat16 bf16;
__device__ __forceinline__ float bf2f(bf16 v) { return __bfloat162float(v); }

// ---------------- zero the counter/accumulator region ------------------------
__global__ void zero_i(int* __restrict__ p, int n) {
    int i = blockIdx.x * 256 + threadIdx.x;
    int st = gridDim.x * 256;
    for (; i < n; i += st) p[i] = 0;
}

// ---------------- padded CSR fill: col[d*CAP + slot] = src --------------------
__global__ void fill_padded(const int* __restrict__ src, const int* __restrict__ dst,
                            int* __restrict__ cnt, int* __restrict__ col) {
    int e = blockIdx.x * 256 + threadIdx.x;       // 6250 * 256 == 1.6M exact
    int d = dst[e];
    int slot = atomicAdd(&cnt[d], 1);             // 16 avg per counter: uncontended
    col[d * CAP + slot] = src[e];
}

// ---------------- per-graph node counts via binary search (batch sorted) -----
__global__ void cntg_bounds(const int* __restrict__ batch, int* __restrict__ cntg) {
    int g = threadIdx.x;                          // 1 block x 128 threads
    int lo = 0, hi = N_NODES;
    while (lo < hi) { int m = (lo + hi) >> 1; if (batch[m] < g) lo = m + 1; else hi = m; }
    int lb = lo;
    lo = 0; hi = N_NODES;
    while (lo < hi) { int m = (lo + hi) >> 1; if (batch[m] < g + 1) lo = m + 1; else hi = m; }
    cntg[g] = lo - lb;
}

// ---------------- layer-0 pre-projection: ybf = bf16(x @ W1f) (no bias) ------
__global__ void proj0(const float* __restrict__ x, const float* __restrict__ W1,
                      bf16* __restrict__ ybf) {
    __shared__ float xsh[4][IN_CH];
    const int wave = threadIdx.x >> 6, lane = threadIdx.x & 63;
    const int n = blockIdx.x * 4 + wave;          // 25000 * 4 == 100000
    float2 xv2 = ((const float2*)(x + (long)n * IN_CH))[lane];
    xsh[wave][2 * lane]     = xv2.x;              // 2-way bank alias: free
    xsh[wave][2 * lane + 1] = xv2.y;
    // per-wave LDS slice: wave-lockstep + compiler lgkmcnt; no barrier
    float acc = 0.f;
    for (int k = 0; k < IN_CH; k += 4) {
        float4 xv = *(const float4*)&xsh[wave][k];
        acc += xv.x * W1[(k + 0) * 64 + lane];
        acc += xv.y * W1[(k + 1) * 64 + lane];
        acc += xv.z * W1[(k + 2) * 64 + lane];
        acc += xv.w * W1[(k + 3) * 64 + lane];
    }
    ybf[(long)n * 64 + lane] = __float2bfloat16(acc);
}

// ---------------- fused layer: gather -> relu -> W2 -> pool (+ next W1) ------
// t = relu( ybf[n] + sum_nb ybf[nb] + b1 );  h = relu(t@W2 + b2)
// pooled_l[rep][batch[n]] += h  (block-aggregated: 1 atomic per block usually)
// if HAS_NEXT: ynext = bf16(h @ W1n)
template <bool HAS_NEXT>
__global__ void layer_fused(const bf16* __restrict__ ybf, const int* __restrict__ cnt,
                            const int* __restrict__ col, const int* __restrict__ batch,
                            const float* __restrict__ b1, const float* __restrict__ W2,
                            const float* __restrict__ b2, const float* __restrict__ W1n,
                            bf16* __restrict__ ynext, float* __restrict__ pooled_l) {
    __shared__ float tsh[4][64];
    __shared__ float hsh[4][64];
    const int wave = threadIdx.x >> 6, lane = threadIdx.x & 63;
    const int nA = blockIdx.x * 4;
    const int n = __builtin_amdgcn_readfirstlane(nA + wave);
    const int deg = __builtin_amdgcn_readfirstlane(cnt[n]);
    const int g = __builtin_amdgcn_readfirstlane(batch[n]);
    const long s = (long)n * CAP;

    float t = bf2f(ybf[(long)n * 64 + lane]) + b1[lane];

    // 16-deep batches: 16 outstanding row-gathers per wave
    int i = 0;
    for (; i + 16 <= deg; i += 16) {
        float f[16];
        #pragma unroll
        for (int u = 0; u < 16; u++) {
            int c = __builtin_amdgcn_readfirstlane(col[s + i + u]);
            f[u] = bf2f(ybf[(long)c * 64 + lane]);
        }
        #pragma unroll
        for (int u = 0; u < 16; u++) t += f[u];
    }
    for (; i + 4 <= deg; i += 4) {
        float f[4];
        #pragma unroll
        for (int u = 0; u < 4; u++) {
            int c = __builtin_amdgcn_readfirstlane(col[s + i + u]);
            f[u] = bf2f(ybf[(long)c * 64 + lane]);
        }
        t += (f[0] + f[1]) + (f[2] + f[3]);
    }
    for (; i < deg; i++) {
        int c = __builtin_amdgcn_readfirstlane(col[s + i]);
        t += bf2f(ybf[(long)c * 64 + lane]);
    }
    t = fmaxf(t, 0.f);
    tsh[wave][lane] = t;          // per-wave slice: no barrier needed here

    float h = b2[lane];
    for (int k = 0; k < 64; k += 4) {
        float4 tv = *(const float4*)&tsh[wave][k];
        h += tv.x * W2[(k + 0) * 64 + lane];
        h += tv.y * W2[(k + 1) * 64 + lane];
        h += tv.z * W2[(k + 2) * 64 + lane];
        h += tv.w * W2[(k + 3) * 64 + lane];
    }
    h = fmaxf(h, 0.f);
    hsh[wave][lane] = h;

    if (HAS_NEXT) {               // reads only own wave's hsh slice: pre-barrier OK
        float yn = 0.f;
        for (int k = 0; k < 64; k += 4) {
            float4 hv = *(const float4*)&hsh[wave][k];
            yn += hv.x * W1n[(k + 0) * 64 + lane];
            yn += hv.y * W1n[(k + 1) * 64 + lane];
            yn += hv.z * W1n[(k + 2) * 64 + lane];
            yn += hv.w * W1n[(k + 3) * 64 + lane];
        }
        ynext[(long)n * 64 + lane] = __float2bfloat16(yn);
    }

    // block-aggregated pool contribution (replicated target cuts chains 8x)
    __syncthreads();
    float* rep = pooled_l + (long)(blockIdx.x & (NREP - 1)) * NUM_GRAPHS * HID;
    const int gA = __builtin_amdgcn_readfirstlane(batch[nA]);
    const int gD = __builtin_amdgcn_readfirstlane(batch[nA + 3]);
    if (gA == gD) {               // 99.5% of blocks: whole block same graph
        if (wave == 0) {
            float sum = (hsh[0][lane] + hsh[1][lane]) + (hsh[2][lane] + hsh[3][lane]);
            atomicAdd(&rep[gA * 64 + lane], sum);
        }
    } else {
        atomicAdd(&rep[g * 64 + lane], h);
    }
}

// ---------------- JK projection on pooled sums (exact: pooling is linear) ----
// pooled_jk[g] = sum_l (sum_r pooled[l][r][g]) @ Wjk_l + cntg[g] * bjk
__global__ void jk_pool(const float* __restrict__ pooled, const int* __restrict__ cntg,
                        const float* __restrict__ Wjk, const float* __restrict__ bjk,
                        float* __restrict__ pooled_jk) {
    __shared__ float sh[64];
    int g = blockIdx.x, j = threadIdx.x;          // 128 blocks x 64 threads (1 wave)
    float acc = (float)cntg[g] * bjk[j];
    for (int l = 0; l < N_LAYERS; l++) {
        float s = 0.f;
        for (int r = 0; r < NREP; r++)
            s += pooled[((long)(l * NREP + r) * NUM_GRAPHS + g) * 64 + j];
        sh[j] = s;                                // single wave: lockstep, no barrier
        const float* W = Wjk + (long)l * HID * 64;
        for (int k = 0; k < 64; k++) acc += sh[k] * W[k * 64 + j];
    }
    pooled_jk[g * 64 + j] = acc;
}

// ---------------- classifier: Linear -> BN(batch stats) -> ReLU -> Linear ----
__global__ void cls_all(const float* __restrict__ pooled_jk,
                        const float* __restrict__ Wc1, const float* __restrict__ bc1,
                        const float* __restrict__ gamma, const float* __restrict__ beta,
                        const float* __restrict__ Wc2, const float* __restrict__ bc2,
                        float* __restrict__ out) {
    __shared__ float Z[NUM_GRAPHS * HID];         // 32 KB
    __shared__ float mu[HID], rs[HID];
    int tid = threadIdx.x;                        // 256

    for (int i = tid; i < NUM_GRAPHS * HID; i += 256) {
        int g = i >> 6, j = i & 63;
        float acc = bc1[j];
        for (int k = 0; k < 64; k++) acc += pooled_jk[g * 64 + k] * Wc1[k * 64 + j];
        Z[i] = acc;
    }
    __syncthreads();
    if (tid < HID) {
        float s = 0.f, sq = 0.f;
        for (int g = 0; g < NUM_GRAPHS; g++) {
            float v = Z[g * 64 + tid];
            s += v; sq += v * v;
        }
        float m = s / NUM_GRAPHS;
        mu[tid] = m;
        rs[tid] = rsqrtf(sq / NUM_GRAPHS - m * m + BN_EPS);
    }
    __syncthreads();
    for (int i = tid; i < NUM_GRAPHS * OUT_CH; i += 256) {
        int g = i / OUT_CH, o = i % OUT_CH;
        float acc = bc2[o];
        for (int j = 0; j < 64; j++) {
            float v = (Z[g * 64 + j] - mu[j]) * rs[j] * gamma[j] + beta[j];
            acc += fmaxf(v, 0.f) * Wc2[j * OUT_CH + o];
        }
        out[i] = acc;
    }
}

// -----------------------------------------------------------------------------
extern "C" void kernel_launch(void* const* d_in, const int* in_sizes, int n_in,
                              void* d_out, int out_size, void* d_ws, size_t ws_size,
                              hipStream_t stream) {
    const float* x     = (const float*)d_in[0];
    const int*   ei    = (const int*)d_in[1];
    const int*   batch = (const int*)d_in[2];
    const float* W1f   = (const float*)d_in[3];
    const float* b1f   = (const float*)d_in[4];
    const float* W2f   = (const float*)d_in[5];
    const float* b2f   = (const float*)d_in[6];
    const float* W1r   = (const float*)d_in[7];
    const float* b1r   = (const float*)d_in[8];
    const float* W2r   = (const float*)d_in[9];
    const float* b2r   = (const float*)d_in[10];
    const float* Wjk   = (const float*)d_in[11];
    const float* bjk   = (const float*)d_in[12];
    const float* Wc1   = (const float*)d_in[13];
    const float* bc1   = (const float*)d_in[14];
    const float* gamma = (const float*)d_in[15];
    const float* beta  = (const float*)d_in[16];
    const float* Wc2   = (const float*)d_in[17];
    const float* bc2   = (const float*)d_in[18];

    const int* src = ei;
    const int* dst = ei + N_EDGES;

    // workspace layout
    float* ws        = (float*)d_ws;
    float* pooled_jk = ws;                                      // 8192 floats
    bf16*  ybfA      = (bf16*)(pooled_jk + NUM_GRAPHS * HID);   // 6.4M bf16
    bf16*  ybfB      = ybfA + (long)N_NODES * HID;              // 6.4M bf16
    int*   cnt       = (int*)(ybfB + (long)N_NODES * HID);      // 100000
    float* pooled    = (float*)(cnt + N_NODES);                 // 4*8*8192 floats
    int*   cntg      = (int*)(pooled + (long)N_LAYERS * NREP * NUM_GRAPHS * HID); // 128
    int*   col       = cntg + NUM_GRAPHS;                       // 6.4M ints
    const int ZN = N_NODES + N_LAYERS * NREP * NUM_GRAPHS * HID; // cnt + pooled

    // ---- build padded CSR + per-graph counts ----
    zero_i<<<360, 256, 0, stream>>>(cnt, ZN);
    fill_padded<<<N_EDGES / 256, 256, 0, stream>>>(src, dst, cnt, col);
    cntg_bounds<<<1, 128, 0, stream>>>(batch, cntg);

    // ---- layer-0 pre-projection (dense, streaming) ----
    const int NB = N_NODES / 4;                                 // 25000
    proj0<<<NB, 256, 0, stream>>>(x, W1f, ybfA);

    // ---- 4 fused layers ----
    const long PL = (long)NREP * NUM_GRAPHS * HID;
    layer_fused<true><<<NB, 256, 0, stream>>>(
        ybfA, cnt, col, batch, b1f, W2f, b2f,
        W1r, ybfB, pooled);
    layer_fused<true><<<NB, 256, 0, stream>>>(
        ybfB, cnt, col, batch, b1r, W2r, b2r,
        W1r + (long)1 * HID * HID, ybfA, pooled + 1 * PL);
    layer_fused<true><<<NB, 256, 0, stream>>>(
        ybfA, cnt, col, batch, b1r + HID, W2r + (long)1 * HID * HID, b2r + HID,
        W1r + (long)2 * HID * HID, ybfB, pooled + 2 * PL);
    layer_fused<false><<<NB, 256, 0, stream>>>(
        ybfB, cnt, col, batch, b1r + 2 * HID, W2r + (long)2 * HID * HID, b2r + 2 * HID,
        nullptr, nullptr, pooled + 3 * PL);

    // ---- JK on pooled sums + classifier ----
    jk_pool<<<NUM_GRAPHS, 64, 0, stream>>>(pooled, cntg, Wjk, bjk, pooled_jk);
    cls_all<<<1, 256, 0, stream>>>(pooled_jk, Wc1, bc1, gamma, beta, Wc2, bc2,
                                   (float*)d_out);
}

// Round 11
// 813.285 us; speedup vs baseline: 2.0006x; 1.0553x over previous
//
#include <hip/hip_runtime.h>
#include <hip/hip_bf16.h>

#define N_NODES    100000
#define N_EDGES    1600000
#define IN_CH      128
#define HID        64
#define N_LAYERS   4
#define OUT_CH     10
#define NUM_GRAPHS 128
#define BN_EPS     1e-5f
#define CAP        64             // padded CSR row capacity; P(deg>64) ~ 1e-19 at Poisson(16)
#define NREP       8              // pooled replicas (cuts per-address atomic chains 8x)
#define NBKT       256            // dst>>9 -> buckets 0..195 (256 slots for pow2 LDS)
#define EPB        2048           // edges per block in partition kernels
#define PNB        782            // ceil(1.6M / 2048)

typedef __hip_bfloat16 bf16;
__device__ __forceinline__ float bf2f(bf16 v) { return __bfloat162float(v); }

// ---------------- zero the counter/accumulator region ------------------------
__global__ void zero_i(int* __restrict__ p, int n) {
    int i = blockIdx.x * 256 + threadIdx.x;
    int st = gridDim.x * 256;
    for (; i < n; i += st) p[i] = 0;
}

// ---------------- bucket histogram (LDS-aggregated) --------------------------
__global__ void bhist(const int* __restrict__ dst, int* __restrict__ ghist) {
    __shared__ int h[NBKT];
    int t = threadIdx.x;
    h[t] = 0;
    __syncthreads();
    long base = (long)blockIdx.x * EPB;
    for (int u = 0; u < 8; u++) {
        long e = base + u * 256 + t;
        if (e < N_EDGES) atomicAdd(&h[dst[e] >> 9], 1);
    }
    __syncthreads();
    if (h[t]) atomicAdd(&ghist[t], h[t]);
}

// ---------------- bucket scan + cntg (binary search) + ybf pad-row zero ------
__global__ void bscan(const int* __restrict__ ghist, int* __restrict__ gcursor,
                      const int* __restrict__ batch, int* __restrict__ cntg,
                      bf16* __restrict__ ybfA, bf16* __restrict__ ybfB) {
    __shared__ int sh[NBKT];
    int t = threadIdx.x;                          // 256 threads
    int v = ghist[t];
    sh[t] = v;
    __syncthreads();
    for (int off = 1; off < NBKT; off <<= 1) {
        int a = (t >= off) ? sh[t - off] : 0;
        __syncthreads();
        sh[t] += a;
        __syncthreads();
    }
    gcursor[t] = sh[t] - v;                       // exclusive bucket base
    if (t < NUM_GRAPHS) {                         // per-graph node counts
        int g = t, lo = 0, hi = N_NODES;
        while (lo < hi) { int m = (lo + hi) >> 1; if (batch[m] < g) lo = m + 1; else hi = m; }
        int lb = lo;
        lo = 0; hi = N_NODES;
        while (lo < hi) { int m = (lo + hi) >> 1; if (batch[m] < g + 1) lo = m + 1; else hi = m; }
        cntg[g] = lo - lb;
    }
    if (t < HID) {                                // sentinel zero-row for tail-free gather
        ybfA[(long)N_NODES * HID + t] = __float2bfloat16(0.f);
        ybfB[(long)N_NODES * HID + t] = __float2bfloat16(0.f);
    }
}

// ---------------- partition edges into bucket order --------------------------
__global__ void bpart(const int* __restrict__ src, const int* __restrict__ dst,
                      int* __restrict__ gcursor, int2* __restrict__ epart) {
    __shared__ int h[NBKT];
    __shared__ int cur[NBKT];
    int t = threadIdx.x;
    h[t] = 0;
    __syncthreads();
    long base = (long)blockIdx.x * EPB;
    int myd[8], mys[8];
    for (int u = 0; u < 8; u++) {
        long e = base + u * 256 + t;
        if (e < N_EDGES) {
            myd[u] = dst[e];
            mys[u] = src[e];
            atomicAdd(&h[myd[u] >> 9], 1);
        } else myd[u] = -1;
    }
    __syncthreads();
    if (h[t]) cur[t] = atomicAdd(&gcursor[t], h[t]);
    __syncthreads();
    for (int u = 0; u < 8; u++) {
        if (myd[u] >= 0) {
            int pos = atomicAdd(&cur[myd[u] >> 9], 1);
            epart[pos] = make_int2(mys[u], myd[u]);
        }
    }
}

// ---------------- fill padded CSR from bucket-sorted edges -------------------
// col writes now fall in a 128-KB window per bucket: L2 absorbs line re-writes.
__global__ void fillp(const int2* __restrict__ epart, int* __restrict__ cnt,
                      int* __restrict__ col) {
    int t = threadIdx.x;
    long base = (long)blockIdx.x * EPB;
    for (int u = 0; u < 8; u++) {
        long e = base + u * 256 + t;
        if (e < N_EDGES) {
            int2 p = epart[e];
            int slot = atomicAdd(&cnt[p.y], 1);
            col[p.y * CAP + slot] = p.x;
        }
    }
}

// ---------------- pad each row to a multiple of 16 with sentinel -------------
__global__ void pad_rows(const int* __restrict__ cnt, int* __restrict__ col) {
    int n = blockIdx.x * 256 + threadIdx.x;       // 391 blocks
    if (n >= N_NODES) return;
    int c = cnt[n];
    int c16 = (c + 15) & ~15;
    for (int s = c; s < c16; s++) col[n * CAP + s] = N_NODES;
}

// ---------------- layer-0 pre-projection: ybf = bf16(x @ W1f) (no bias) ------
__global__ void proj0(const float* __restrict__ x, const float* __restrict__ W1,
                      bf16* __restrict__ ybf) {
    __shared__ float xsh[4][IN_CH];
    const int wave = threadIdx.x >> 6, lane = threadIdx.x & 63;
    const int n = blockIdx.x * 4 + wave;          // 25000 * 4 == 100000
    float2 xv2 = ((const float2*)(x + (long)n * IN_CH))[lane];
    xsh[wave][2 * lane]     = xv2.x;              // 2-way bank alias: free
    xsh[wave][2 * lane + 1] = xv2.y;
    // per-wave LDS slice: wave-lockstep + compiler lgkmcnt; no barrier
    float acc = 0.f;
    for (int k = 0; k < IN_CH; k += 4) {
        float4 xv = *(const float4*)&xsh[wave][k];
        acc += xv.x * W1[(k + 0) * 64 + lane];
        acc += xv.y * W1[(k + 1) * 64 + lane];
        acc += xv.z * W1[(k + 2) * 64 + lane];
        acc += xv.w * W1[(k + 3) * 64 + lane];
    }
    ybf[(long)n * 64 + lane] = __float2bfloat16(acc);
}

// ---------------- fused layer: gather -> relu -> W2 -> pool (+ next W1) ------
// Tail-free: deg rounded to x16, pad slots point at the sentinel zero-row.
template <bool HAS_NEXT>
__global__ void layer_fused(const bf16* __restrict__ ybf, const int* __restrict__ cnt,
                            const int* __restrict__ col, const int* __restrict__ batch,
                            const float* __restrict__ b1, const float* __restrict__ W2,
                            const float* __restrict__ b2, const float* __restrict__ W1n,
                            bf16* __restrict__ ynext, float* __restrict__ pooled_l) {
    __shared__ float tsh[4][64];
    __shared__ float hsh[4][64];
    const int wave = threadIdx.x >> 6, lane = threadIdx.x & 63;
    const int nA = blockIdx.x * 4;
    const int n = __builtin_amdgcn_readfirstlane(nA + wave);
    const int deg16 = __builtin_amdgcn_readfirstlane((cnt[n] + 15) & ~15);
    const int g = __builtin_amdgcn_readfirstlane(batch[n]);
    const long s = (long)n * CAP;

    float t = bf2f(ybf[(long)n * 64 + lane]) + b1[lane];

    for (int i = 0; i < deg16; i += 16) {
        float f[16];
        #pragma unroll
        for (int u = 0; u < 16; u++) {
            int c = __builtin_amdgcn_readfirstlane(col[s + i + u]);
            f[u] = bf2f(ybf[(long)c * 64 + lane]);
        }
        #pragma unroll
        for (int u = 0; u < 16; u++) t += f[u];
    }
    t = fmaxf(t, 0.f);
    tsh[wave][lane] = t;          // per-wave slice: no barrier needed here

    float h = b2[lane];
    for (int k = 0; k < 64; k += 4) {
        float4 tv = *(const float4*)&tsh[wave][k];
        h += tv.x * W2[(k + 0) * 64 + lane];
        h += tv.y * W2[(k + 1) * 64 + lane];
        h += tv.z * W2[(k + 2) * 64 + lane];
        h += tv.w * W2[(k + 3) * 64 + lane];
    }
    h = fmaxf(h, 0.f);
    hsh[wave][lane] = h;

    if (HAS_NEXT) {               // reads only own wave's hsh slice: pre-barrier OK
        float yn = 0.f;
        for (int k = 0; k < 64; k += 4) {
            float4 hv = *(const float4*)&hsh[wave][k];
            yn += hv.x * W1n[(k + 0) * 64 + lane];
            yn += hv.y * W1n[(k + 1) * 64 + lane];
            yn += hv.z * W1n[(k + 2) * 64 + lane];
            yn += hv.w * W1n[(k + 3) * 64 + lane];
        }
        ynext[(long)n * 64 + lane] = __float2bfloat16(yn);
    }

    // block-aggregated pool contribution (replicated target cuts chains 8x)
    __syncthreads();
    float* rep = pooled_l + (long)(blockIdx.x & (NREP - 1)) * NUM_GRAPHS * HID;
    const int gA = __builtin_amdgcn_readfirstlane(batch[nA]);
    const int gD = __builtin_amdgcn_readfirstlane(batch[nA + 3]);
    if (gA == gD) {               // 99.5% of blocks: whole block same graph
        if (wave == 0) {
            float sum = (hsh[0][lane] + hsh[1][lane]) + (hsh[2][lane] + hsh[3][lane]);
            atomicAdd(&rep[gA * 64 + lane], sum);
        }
    } else {
        atomicAdd(&rep[g * 64 + lane], h);
    }
}

// ---------------- JK projection on pooled sums (exact: pooling is linear) ----
__global__ void jk_pool(const float* __restrict__ pooled, const int* __restrict__ cntg,
                        const float* __restrict__ Wjk, const float* __restrict__ bjk,
                        float* __restrict__ pooled_jk) {
    __shared__ float sh[64];
    int g = blockIdx.x, j = threadIdx.x;          // 128 blocks x 64 threads (1 wave)
    float acc = (float)cntg[g] * bjk[j];
    for (int l = 0; l < N_LAYERS; l++) {
        float s = 0.f;
        for (int r = 0; r < NREP; r++)
            s += pooled[((long)(l * NREP + r) * NUM_GRAPHS + g) * 64 + j];
        sh[j] = s;                                // single wave: lockstep, no barrier
        const float* W = Wjk + (long)l * HID * 64;
        for (int k = 0; k < 64; k++) acc += sh[k] * W[k * 64 + j];
    }
    pooled_jk[g * 64 + j] = acc;
}

// ---------------- classifier: Linear -> BN(batch stats) -> ReLU -> Linear ----
__global__ void cls_all(const float* __restrict__ pooled_jk,
                        const float* __restrict__ Wc1, const float* __restrict__ bc1,
                        const float* __restrict__ gamma, const float* __restrict__ beta,
                        const float* __restrict__ Wc2, const float* __restrict__ bc2,
                        float* __restrict__ out) {
    __shared__ float Z[NUM_GRAPHS * HID];         // 32 KB
    __shared__ float mu[HID], rs[HID];
    int tid = threadIdx.x;                        // 256

    for (int i = tid; i < NUM_GRAPHS * HID; i += 256) {
        int g = i >> 6, j = i & 63;
        float acc = bc1[j];
        for (int k = 0; k < 64; k++) acc += pooled_jk[g * 64 + k] * Wc1[k * 64 + j];
        Z[i] = acc;
    }
    __syncthreads();
    if (tid < HID) {
        float s = 0.f, sq = 0.f;
        for (int g = 0; g < NUM_GRAPHS; g++) {
            float v = Z[g * 64 + tid];
            s += v; sq += v * v;
        }
        float m = s / NUM_GRAPHS;
        mu[tid] = m;
        rs[tid] = rsqrtf(sq / NUM_GRAPHS - m * m + BN_EPS);
    }
    __syncthreads();
    for (int i = tid; i < NUM_GRAPHS * OUT_CH; i += 256) {
        int g = i / OUT_CH, o = i % OUT_CH;
        float acc = bc2[o];
        for (int j = 0; j < 64; j++) {
            float v = (Z[g * 64 + j] - mu[j]) * rs[j] * gamma[j] + beta[j];
            acc += fmaxf(v, 0.f) * Wc2[j * OUT_CH + o];
        }
        out[i] = acc;
    }
}

// -----------------------------------------------------------------------------
extern "C" void kernel_launch(void* const* d_in, const int* in_sizes, int n_in,
                              void* d_out, int out_size, void* d_ws, size_t ws_size,
                              hipStream_t stream) {
    const float* x     = (const float*)d_in[0];
    const int*   ei    = (const int*)d_in[1];
    const int*   batch = (const int*)d_in[2];
    const float* W1f   = (const float*)d_in[3];
    const float* b1f   = (const float*)d_in[4];
    const float* W2f   = (const float*)d_in[5];
    const float* b2f   = (const float*)d_in[6];
    const float* W1r   = (const float*)d_in[7];
    const float* b1r   = (const float*)d_in[8];
    const float* W2r   = (const float*)d_in[9];
    const float* b2r   = (const float*)d_in[10];
    const float* Wjk   = (const float*)d_in[11];
    const float* bjk   = (const float*)d_in[12];
    const float* Wc1   = (const float*)d_in[13];
    const float* bc1   = (const float*)d_in[14];
    const float* gamma = (const float*)d_in[15];
    const float* beta  = (const float*)d_in[16];
    const float* Wc2   = (const float*)d_in[17];
    const float* bc2   = (const float*)d_in[18];

    const int* src = ei;
    const int* dst = ei + N_EDGES;

    // workspace layout (all segments 8-B aligned)
    float* ws        = (float*)d_ws;
    float* pooled_jk = ws;                                      // 8192 floats
    bf16*  ybfA      = (bf16*)(pooled_jk + NUM_GRAPHS * HID);   // (N+1)*64 bf16
    bf16*  ybfB      = ybfA + (long)(N_NODES + 1) * HID;        // (N+1)*64 bf16
    int*   cnt       = (int*)(ybfB + (long)(N_NODES + 1) * HID);// 100000
    float* pooled    = (float*)(cnt + N_NODES);                 // 4*8*8192 floats
    int*   ghist     = (int*)(pooled + (long)N_LAYERS * NREP * NUM_GRAPHS * HID); // 256
    int*   gcursor   = ghist + NBKT;                            // 256
    int*   cntg      = gcursor + NBKT;                          // 128
    int*   col       = cntg + NUM_GRAPHS;                       // 6.4M ints
    int2*  epart     = (int2*)(col + (long)N_NODES * CAP);      // 1.6M int2
    const int ZN = N_NODES + N_LAYERS * NREP * NUM_GRAPHS * HID + 2 * NBKT;

    // ---- CSR build: zero -> bucket hist -> scan -> partition -> fill -> pad --
    zero_i<<<360, 256, 0, stream>>>(cnt, ZN);
    bhist<<<PNB, 256, 0, stream>>>(dst, ghist);
    bscan<<<1, 256, 0, stream>>>(ghist, gcursor, batch, cntg, ybfA, ybfB);
    bpart<<<PNB, 256, 0, stream>>>(src, dst, gcursor, epart);
    fillp<<<PNB, 256, 0, stream>>>(epart, cnt, col);
    pad_rows<<<(N_NODES + 255) / 256, 256, 0, stream>>>(cnt, col);

    // ---- layer-0 pre-projection (dense, streaming) ----
    const int NB = N_NODES / 4;                                 // 25000
    proj0<<<NB, 256, 0, stream>>>(x, W1f, ybfA);

    // ---- 4 fused layers ----
    const long PL = (long)NREP * NUM_GRAPHS * HID;
    layer_fused<true><<<NB, 256, 0, stream>>>(
        ybfA, cnt, col, batch, b1f, W2f, b2f,
        W1r, ybfB, pooled);
    layer_fused<true><<<NB, 256, 0, stream>>>(
        ybfB, cnt, col, batch, b1r, W2r, b2r,
        W1r + (long)1 * HID * HID, ybfA, pooled + 1 * PL);
    layer_fused<true><<<NB, 256, 0, stream>>>(
        ybfA, cnt, col, batch, b1r + HID, W2r + (long)1 * HID * HID, b2r + HID,
        W1r + (long)2 * HID * HID, ybfB, pooled + 2 * PL);
    layer_fused<false><<<NB, 256, 0, stream>>>(
        ybfB, cnt, col, batch, b1r + 2 * HID, W2r + (long)2 * HID * HID, b2r + 2 * HID,
        nullptr, nullptr, pooled + 3 * PL);

    // ---- JK on pooled sums + classifier ----
    jk_pool<<<NUM_GRAPHS, 64, 0, stream>>>(pooled, cntg, Wjk, bjk, pooled_jk);
    cls_all<<<1, 256, 0, stream>>>(pooled_jk, Wc1, bc1, gamma, beta, Wc2, bc2,
                                   (float*)d_out);
}

// Round 12
// 722.918 us; speedup vs baseline: 2.2507x; 1.1250x over previous
//
#include <hip/hip_runtime.h>
#include <hip/hip_bf16.h>

#define N_NODES    100000
#define N_EDGES    1600000
#define IN_CH      128
#define HID        64
#define N_LAYERS   4
#define OUT_CH     10
#define NUM_GRAPHS 128
#define BN_EPS     1e-5f
#define CAP        64             // padded CSR row capacity; P(deg>64) ~ 1e-19 at Poisson(16)
#define NREP       8              // pooled replicas (cuts per-address atomic chains 8x)
#define NBKT       256            // dst>>9 -> buckets 0..195 (256 slots for pow2 LDS)
#define EPB        2048           // edges per block in partition kernels
#define PNB        782            // ceil(1.6M / 2048)

typedef __hip_bfloat16 bf16;
typedef unsigned int uint32;

__device__ __forceinline__ float bf2f(bf16 v) { return __bfloat162float(v); }
// unpack packed bf16x2 dword -> float2 (bf16 -> f32 is <<16)
__device__ __forceinline__ float2 unpk(uint32 p) {
    float2 r;
    r.x = __uint_as_float(p << 16);
    r.y = __uint_as_float(p & 0xffff0000u);
    return r;
}

// ---------------- zero the counter/accumulator region ------------------------
__global__ void zero_i(int* __restrict__ p, int n) {
    int i = blockIdx.x * 256 + threadIdx.x;
    int st = gridDim.x * 256;
    for (; i < n; i += st) p[i] = 0;
}

// ---------------- bucket histogram (LDS-aggregated) --------------------------
__global__ void bhist(const int* __restrict__ dst, int* __restrict__ ghist) {
    __shared__ int h[NBKT];
    int t = threadIdx.x;
    h[t] = 0;
    __syncthreads();
    long base = (long)blockIdx.x * EPB;
    for (int u = 0; u < 8; u++) {
        long e = base + u * 256 + t;
        if (e < N_EDGES) atomicAdd(&h[dst[e] >> 9], 1);
    }
    __syncthreads();
    if (h[t]) atomicAdd(&ghist[t], h[t]);
}

// ---------------- bucket scan + cntg (binary search) + ybf pad-row zero ------
__global__ void bscan(const int* __restrict__ ghist, int* __restrict__ gcursor,
                      const int* __restrict__ batch, int* __restrict__ cntg,
                      bf16* __restrict__ ybfA, bf16* __restrict__ ybfB) {
    __shared__ int sh[NBKT];
    int t = threadIdx.x;                          // 256 threads
    int v = ghist[t];
    sh[t] = v;
    __syncthreads();
    for (int off = 1; off < NBKT; off <<= 1) {
        int a = (t >= off) ? sh[t - off] : 0;
        __syncthreads();
        sh[t] += a;
        __syncthreads();
    }
    gcursor[t] = sh[t] - v;                       // exclusive bucket base
    if (t < NUM_GRAPHS) {                         // per-graph node counts
        int g = t, lo = 0, hi = N_NODES;
        while (lo < hi) { int m = (lo + hi) >> 1; if (batch[m] < g) lo = m + 1; else hi = m; }
        int lb = lo;
        lo = 0; hi = N_NODES;
        while (lo < hi) { int m = (lo + hi) >> 1; if (batch[m] < g + 1) lo = m + 1; else hi = m; }
        cntg[g] = lo - lb;
    }
    if (t < HID) {                                // sentinel zero-row for tail-free gather
        ybfA[(long)N_NODES * HID + t] = __float2bfloat16(0.f);
        ybfB[(long)N_NODES * HID + t] = __float2bfloat16(0.f);
    }
}

// ---------------- partition edges into bucket order --------------------------
__global__ void bpart(const int* __restrict__ src, const int* __restrict__ dst,
                      int* __restrict__ gcursor, int2* __restrict__ epart) {
    __shared__ int h[NBKT];
    __shared__ int cur[NBKT];
    int t = threadIdx.x;
    h[t] = 0;
    __syncthreads();
    long base = (long)blockIdx.x * EPB;
    int myd[8], mys[8];
    for (int u = 0; u < 8; u++) {
        long e = base + u * 256 + t;
        if (e < N_EDGES) {
            myd[u] = dst[e];
            mys[u] = src[e];
            atomicAdd(&h[myd[u] >> 9], 1);
        } else myd[u] = -1;
    }
    __syncthreads();
    if (h[t]) cur[t] = atomicAdd(&gcursor[t], h[t]);
    __syncthreads();
    for (int u = 0; u < 8; u++) {
        if (myd[u] >= 0) {
            int pos = atomicAdd(&cur[myd[u] >> 9], 1);
            epart[pos] = make_int2(mys[u], myd[u]);
        }
    }
}

// ---------------- fill padded CSR from bucket-sorted edges -------------------
__global__ void fillp(const int2* __restrict__ epart, int* __restrict__ cnt,
                      int* __restrict__ col) {
    int t = threadIdx.x;
    long base = (long)blockIdx.x * EPB;
    for (int u = 0; u < 8; u++) {
        long e = base + u * 256 + t;
        if (e < N_EDGES) {
            int2 p = epart[e];
            int slot = atomicAdd(&cnt[p.y], 1);
            col[p.y * CAP + slot] = p.x;
        }
    }
}

// ---------------- pad each row to a multiple of 32 with sentinel -------------
__global__ void pad_rows(const int* __restrict__ cnt, int* __restrict__ col) {
    int n = blockIdx.x * 256 + threadIdx.x;       // 391 blocks
    if (n >= N_NODES) return;
    int c = cnt[n];
    int c32 = (c + 31) & ~31;
    for (int s = c; s < c32; s++) col[n * CAP + s] = N_NODES;
}

// ---------------- layer-0 pre-projection: ybf = bf16(x @ W1f) (no bias) ------
// 4 nodes per wave: W1 column loads amortized 4x.
__global__ void proj0(const float* __restrict__ x, const float* __restrict__ W1,
                      bf16* __restrict__ ybf) {
    __shared__ float xsh[4][4][IN_CH];            // 8 KB
    const int wave = threadIdx.x >> 6, lane = threadIdx.x & 63;
    const int nb = blockIdx.x * 16 + wave * 4;    // 6250 * 16 == 100000
    #pragma unroll
    for (int r = 0; r < 4; r++) {
        float2 v = ((const float2*)(x + (long)(nb + r) * IN_CH))[lane];
        xsh[wave][r][2 * lane]     = v.x;         // 2-way bank alias: free
        xsh[wave][r][2 * lane + 1] = v.y;
    }
    // per-wave LDS slice: wave-lockstep + compiler lgkmcnt; no barrier
    float a0 = 0.f, a1 = 0.f, a2 = 0.f, a3 = 0.f;
    for (int k = 0; k < IN_CH; k += 4) {
        float4 q0 = *(const float4*)&xsh[wave][0][k];
        float4 q1 = *(const float4*)&xsh[wave][1][k];
        float4 q2 = *(const float4*)&xsh[wave][2][k];
        float4 q3 = *(const float4*)&xsh[wave][3][k];
        float w0 = W1[(k + 0) * 64 + lane];
        float w1 = W1[(k + 1) * 64 + lane];
        float w2 = W1[(k + 2) * 64 + lane];
        float w3 = W1[(k + 3) * 64 + lane];
        a0 += q0.x * w0 + q0.y * w1 + q0.z * w2 + q0.w * w3;
        a1 += q1.x * w0 + q1.y * w1 + q1.z * w2 + q1.w * w3;
        a2 += q2.x * w0 + q2.y * w1 + q2.z * w2 + q2.w * w3;
        a3 += q3.x * w0 + q3.y * w1 + q3.z * w2 + q3.w * w3;
    }
    ybf[(long)(nb + 0) * 64 + lane] = __float2bfloat16(a0);
    ybf[(long)(nb + 1) * 64 + lane] = __float2bfloat16(a1);
    ybf[(long)(nb + 2) * 64 + lane] = __float2bfloat16(a2);
    ybf[(long)(nb + 3) * 64 + lane] = __float2bfloat16(a3);
}

// ---------------- fused layer: dual-row gather -> relu -> W2 -> pool (+W1n) --
// Lanes 0-31 gather row c0 (packed bf16x2), lanes 32-63 row c1: one vmem
// instruction fetches TWO 128-B rows. Halves combine via per-wave LDS.
template <bool HAS_NEXT>
__global__ void layer_fused(const bf16* __restrict__ ybf, const int* __restrict__ cnt,
                            const int* __restrict__ col, const int* __restrict__ batch,
                            const float* __restrict__ b1, const float* __restrict__ W2,
                            const float* __restrict__ b2, const float* __restrict__ W1n,
                            bf16* __restrict__ ynext, float* __restrict__ pooled_l) {
    __shared__ float csh[4][2][2 * HID];          // half-sums, 4 KB
    __shared__ float tsh[4][64];
    __shared__ float hsh[4][64];
    const int wave = threadIdx.x >> 6, lane = threadIdx.x & 63;
    const int hl = lane & 31;
    const bool hi = lane >= 32;
    const int nA = blockIdx.x * 4;
    const int n = __builtin_amdgcn_readfirstlane(nA + wave);
    const int deg32 = __builtin_amdgcn_readfirstlane((cnt[n] + 31) & ~31);
    const int g = __builtin_amdgcn_readfirstlane(batch[n]);
    const long s = (long)n * CAP;
    const uint32* yrow = (const uint32*)ybf;

    float2 a0 = {0.f, 0.f}, a1 = {0.f, 0.f}, a2 = {0.f, 0.f}, a3 = {0.f, 0.f};
    for (int i = 0; i < deg32; i += 32) {
        uint32 p[16];
        #pragma unroll
        for (int u = 0; u < 16; u++) {
            int c0 = __builtin_amdgcn_readfirstlane(col[s + i + 2 * u]);
            int c1 = __builtin_amdgcn_readfirstlane(col[s + i + 2 * u + 1]);
            int c = hi ? c1 : c0;
            p[u] = yrow[(long)c * 32 + hl];
        }
        #pragma unroll
        for (int u = 0; u < 16; u++) {
            float2 f = unpk(p[u]);
            if ((u & 3) == 0) { a0.x += f.x; a0.y += f.y; }
            else if ((u & 3) == 1) { a1.x += f.x; a1.y += f.y; }
            else if ((u & 3) == 2) { a2.x += f.x; a2.y += f.y; }
            else { a3.x += f.x; a3.y += f.y; }
        }
    }
    float2 hs;
    hs.x = (a0.x + a1.x) + (a2.x + a3.x);
    hs.y = (a0.y + a1.y) + (a2.y + a3.y);
    ((float2*)&csh[wave][hi ? 1 : 0][0])[hl] = hs;   // channels (2hl, 2hl+1)
    // per-wave slice: lockstep + compiler lgkmcnt; no barrier
    float t = bf2f(ybf[(long)n * 64 + lane]) + b1[lane]
            + csh[wave][0][lane] + csh[wave][1][lane];
    t = fmaxf(t, 0.f);
    tsh[wave][lane] = t;

    float h = b2[lane];
    for (int k = 0; k < 64; k += 4) {
        float4 tv = *(const float4*)&tsh[wave][k];
        h += tv.x * W2[(k + 0) * 64 + lane];
        h += tv.y * W2[(k + 1) * 64 + lane];
        h += tv.z * W2[(k + 2) * 64 + lane];
        h += tv.w * W2[(k + 3) * 64 + lane];
    }
    h = fmaxf(h, 0.f);
    hsh[wave][lane] = h;

    if (HAS_NEXT) {               // reads only own wave's hsh slice: pre-barrier OK
        float yn = 0.f;
        for (int k = 0; k < 64; k += 4) {
            float4 hv = *(const float4*)&hsh[wave][k];
            yn += hv.x * W1n[(k + 0) * 64 + lane];
            yn += hv.y * W1n[(k + 1) * 64 + lane];
            yn += hv.z * W1n[(k + 2) * 64 + lane];
            yn += hv.w * W1n[(k + 3) * 64 + lane];
        }
        ynext[(long)n * 64 + lane] = __float2bfloat16(yn);
    }

    // block-aggregated pool contribution (replicated target cuts chains 8x)
    __syncthreads();
    float* rep = pooled_l + (long)(blockIdx.x & (NREP - 1)) * NUM_GRAPHS * HID;
    const int gA = __builtin_amdgcn_readfirstlane(batch[nA]);
    const int gD = __builtin_amdgcn_readfirstlane(batch[nA + 3]);
    if (gA == gD) {               // 99.5% of blocks: whole block same graph
        if (wave == 0) {
            float sum = (hsh[0][lane] + hsh[1][lane]) + (hsh[2][lane] + hsh[3][lane]);
            atomicAdd(&rep[gA * 64 + lane], sum);
        }
    } else {
        atomicAdd(&rep[g * 64 + lane], h);
    }
}

// ---------------- JK projection on pooled sums (exact: pooling is linear) ----
__global__ void jk_pool(const float* __restrict__ pooled, const int* __restrict__ cntg,
                        const float* __restrict__ Wjk, const float* __restrict__ bjk,
                        float* __restrict__ pooled_jk) {
    __shared__ float sh[64];
    int g = blockIdx.x, j = threadIdx.x;          // 128 blocks x 64 threads (1 wave)
    float acc = (float)cntg[g] * bjk[j];
    for (int l = 0; l < N_LAYERS; l++) {
        float s = 0.f;
        for (int r = 0; r < NREP; r++)
            s += pooled[((long)(l * NREP + r) * NUM_GRAPHS + g) * 64 + j];
        sh[j] = s;                                // single wave: lockstep, no barrier
        const float* W = Wjk + (long)l * HID * 64;
        for (int k = 0; k < 64; k++) acc += sh[k] * W[k * 64 + j];
    }
    pooled_jk[g * 64 + j] = acc;
}

// ---------------- classifier: Linear -> BN(batch stats) -> ReLU -> Linear ----
__global__ void cls_all(const float* __restrict__ pooled_jk,
                        const float* __restrict__ Wc1, const float* __restrict__ bc1,
                        const float* __restrict__ gamma, const float* __restrict__ beta,
                        const float* __restrict__ Wc2, const float* __restrict__ bc2,
                        float* __restrict__ out) {
    __shared__ float Z[NUM_GRAPHS * HID];         // 32 KB
    __shared__ float mu[HID], rs[HID];
    int tid = threadIdx.x;                        // 256

    for (int i = tid; i < NUM_GRAPHS * HID; i += 256) {
        int g = i >> 6, j = i & 63;
        float acc = bc1[j];
        for (int k = 0; k < 64; k++) acc += pooled_jk[g * 64 + k] * Wc1[k * 64 + j];
        Z[i] = acc;
    }
    __syncthreads();
    if (tid < HID) {
        float s = 0.f, sq = 0.f;
        for (int g = 0; g < NUM_GRAPHS; g++) {
            float v = Z[g * 64 + tid];
            s += v; sq += v * v;
        }
        float m = s / NUM_GRAPHS;
        mu[tid] = m;
        rs[tid] = rsqrtf(sq / NUM_GRAPHS - m * m + BN_EPS);
    }
    __syncthreads();
    for (int i = tid; i < NUM_GRAPHS * OUT_CH; i += 256) {
        int g = i / OUT_CH, o = i % OUT_CH;
        float acc = bc2[o];
        for (int j = 0; j < 64; j++) {
            float v = (Z[g * 64 + j] - mu[j]) * rs[j] * gamma[j] + beta[j];
            acc += fmaxf(v, 0.f) * Wc2[j * OUT_CH + o];
        }
        out[i] = acc;
    }
}

// -----------------------------------------------------------------------------
extern "C" void kernel_launch(void* const* d_in, const int* in_sizes, int n_in,
                              void* d_out, int out_size, void* d_ws, size_t ws_size,
                              hipStream_t stream) {
    const float* x     = (const float*)d_in[0];
    const int*   ei    = (const int*)d_in[1];
    const int*   batch = (const int*)d_in[2];
    const float* W1f   = (const float*)d_in[3];
    const float* b1f   = (const float*)d_in[4];
    const float* W2f   = (const float*)d_in[5];
    const float* b2f   = (const float*)d_in[6];
    const float* W1r   = (const float*)d_in[7];
    const float* b1r   = (const float*)d_in[8];
    const float* W2r   = (const float*)d_in[9];
    const float* b2r   = (const float*)d_in[10];
    const float* Wjk   = (const float*)d_in[11];
    const float* bjk   = (const float*)d_in[12];
    const float* Wc1   = (const float*)d_in[13];
    const float* bc1   = (const float*)d_in[14];
    const float* gamma = (const float*)d_in[15];
    const float* beta  = (const float*)d_in[16];
    const float* Wc2   = (const float*)d_in[17];
    const float* bc2   = (const float*)d_in[18];

    const int* src = ei;
    const int* dst = ei + N_EDGES;

    // workspace layout (all segments 8-B aligned)
    float* ws        = (float*)d_ws;
    float* pooled_jk = ws;                                      // 8192 floats
    bf16*  ybfA      = (bf16*)(pooled_jk + NUM_GRAPHS * HID);   // (N+1)*64 bf16
    bf16*  ybfB      = ybfA + (long)(N_NODES + 1) * HID;        // (N+1)*64 bf16
    int*   cnt       = (int*)(ybfB + (long)(N_NODES + 1) * HID);// 100000
    float* pooled    = (float*)(cnt + N_NODES);                 // 4*8*8192 floats
    int*   ghist     = (int*)(pooled + (long)N_LAYERS * NREP * NUM_GRAPHS * HID); // 256
    int*   gcursor   = ghist + NBKT;                            // 256
    int*   cntg      = gcursor + NBKT;                          // 128
    int*   col       = cntg + NUM_GRAPHS;                       // 6.4M ints
    int2*  epart     = (int2*)(col + (long)N_NODES * CAP);      // 1.6M int2
    const int ZN = N_NODES + N_LAYERS * NREP * NUM_GRAPHS * HID + 2 * NBKT;

    // ---- CSR build: zero -> bucket hist -> scan -> partition -> fill -> pad --
    zero_i<<<360, 256, 0, stream>>>(cnt, ZN);
    bhist<<<PNB, 256, 0, stream>>>(dst, ghist);
    bscan<<<1, 256, 0, stream>>>(ghist, gcursor, batch, cntg, ybfA, ybfB);
    bpart<<<PNB, 256, 0, stream>>>(src, dst, gcursor, epart);
    fillp<<<PNB, 256, 0, stream>>>(epart, cnt, col);
    pad_rows<<<(N_NODES + 255) / 256, 256, 0, stream>>>(cnt, col);

    // ---- layer-0 pre-projection (dense, streaming; 4 nodes/wave) ----
    proj0<<<N_NODES / 16, 256, 0, stream>>>(x, W1f, ybfA);

    // ---- 4 fused layers ----
    const int NB = N_NODES / 4;                                 // 25000
    const long PL = (long)NREP * NUM_GRAPHS * HID;
    layer_fused<true><<<NB, 256, 0, stream>>>(
        ybfA, cnt, col, batch, b1f, W2f, b2f,
        W1r, ybfB, pooled);
    layer_fused<true><<<NB, 256, 0, stream>>>(
        ybfB, cnt, col, batch, b1r, W2r, b2r,
        W1r + (long)1 * HID * HID, ybfA, pooled + 1 * PL);
    layer_fused<true><<<NB, 256, 0, stream>>>(
        ybfA, cnt, col, batch, b1r + HID, W2r + (long)1 * HID * HID, b2r + HID,
        W1r + (long)2 * HID * HID, ybfB, pooled + 2 * PL);
    layer_fused<false><<<NB, 256, 0, stream>>>(
        ybfB, cnt, col, batch, b1r + 2 * HID, W2r + (long)2 * HID * HID, b2r + 2 * HID,
        nullptr, nullptr, pooled + 3 * PL);

    // ---- JK on pooled sums + classifier ----
    jk_pool<<<NUM_GRAPHS, 64, 0, stream>>>(pooled, cntg, Wjk, bjk, pooled_jk);
    cls_all<<<1, 256, 0, stream>>>(pooled_jk, Wc1, bc1, gamma, beta, Wc2, bc2,
                                   (float*)d_out);
}